// Round 10
// baseline (631.375 us; speedup 1.0000x reference)
//
#include <hip/hip_runtime.h>
#include <hip/hip_bf16.h>

#define N_NODES   50000
#define N_EDGES   800000
#define IN_DIM    128
#define EDGE_DIM  32
#define HIDDEN    128
#define NUM_LAYERS 3
#define BN_EPS    1e-5f
#define RES_SCALE 0.1f

typedef unsigned int   u32;
typedef unsigned short u16;
typedef _Float16 half2_t __attribute__((ext_vector_type(2)));
typedef _Float16 half8 __attribute__((ext_vector_type(8)));
typedef unsigned int u32x4 __attribute__((ext_vector_type(4)));
typedef float f32x4 __attribute__((ext_vector_type(4)));

#define AS4 __attribute__((address_space(4)))

__device__ __forceinline__ half2_t as_half2(u32 v) {
    union { u32 u; half2_t h; } c; c.u = v; return c.h;
}
__device__ __forceinline__ u32 pack_half2(float a, float b) {
    union { u32 u; half2_t h; } c;
    c.h.x = (_Float16)a; c.h.y = (_Float16)b; return c.u;
}

// ---------------- pack x -> h16p ; zero deg ; zero stats ----------------
// h16p layout: word w = li*4+q (li=0..15, q=0..3) holds fp16 pair
// (feat q*16+li, feat 64+q*16+li) -> agg gathers are one dwordx4 per lane.
__global__ __launch_bounds__(256) void init_kernel(const float* __restrict__ x,
                                                   u32* __restrict__ h16,
                                                   u32* __restrict__ deg,
                                                   float* __restrict__ statsAll) {
    int idx = blockIdx.x * 256 + threadIdx.x;
    if (idx < N_NODES * 64) {
        int n = idx >> 6, w = idx & 63;
        int li = w >> 2, q = w & 3;
        int f = q * 16 + li;
        h16[idx] = pack_half2(x[n * HIDDEN + f], x[n * HIDDEN + 64 + f]);
    }
    if (idx < N_NODES) deg[idx] = 0u;
    if (idx < NUM_LAYERS * 256) statsAll[idx] = 0.f;
}

// ---------------- degree histogram ----------------
__global__ __launch_bounds__(256) void hist_kernel(const int* __restrict__ ei,
                                                   u32* __restrict__ deg) {
    int e = blockIdx.x * 256 + threadIdx.x;
    if (e < N_EDGES) atomicAdd(&deg[ei[N_EDGES + e]], 1u);
}

// ---------------- multi-block exclusive scan (3 passes) ----------------
#define SCAN_NB ((N_NODES + 255) / 256)   // 196

__global__ __launch_bounds__(256) void scan1_kernel(const u32* __restrict__ deg,
                                                    u32* __restrict__ bsum) {
    int i = blockIdx.x * 256 + threadIdx.x;
    u32 v = (i < N_NODES) ? deg[i] : 0u;
    v += __shfl_down(v, 32, 64);
    v += __shfl_down(v, 16, 64);
    v += __shfl_down(v, 8, 64);
    v += __shfl_down(v, 4, 64);
    v += __shfl_down(v, 2, 64);
    v += __shfl_down(v, 1, 64);
    __shared__ u32 ws[4];
    if ((threadIdx.x & 63) == 0) ws[threadIdx.x >> 6] = v;
    __syncthreads();
    if (threadIdx.x == 0) bsum[blockIdx.x] = ws[0] + ws[1] + ws[2] + ws[3];
}

__global__ __launch_bounds__(256) void scan2_kernel(const u32* __restrict__ bsum,
                                                    u32* __restrict__ bbase,
                                                    u32* __restrict__ off) {
    __shared__ u32 tmp[256];
    int t = threadIdx.x;
    u32 v = (t < SCAN_NB) ? bsum[t] : 0u;
    tmp[t] = v;
    __syncthreads();
    for (int d = 1; d < 256; d <<= 1) {
        u32 u = (t >= d) ? tmp[t - d] : 0u;
        __syncthreads();
        tmp[t] += u;
        __syncthreads();
    }
    if (t < SCAN_NB) bbase[t] = (t == 0) ? 0u : tmp[t - 1];
    if (t == 255) off[N_NODES] = tmp[255];   // grand total
}

__global__ __launch_bounds__(256) void scan3_kernel(const u32* __restrict__ deg,
                                                    const u32* __restrict__ bbase,
                                                    u32* __restrict__ off,
                                                    u32* __restrict__ cursor) {
    __shared__ u32 tmp[256];
    int t = threadIdx.x;
    int i = blockIdx.x * 256 + t;
    u32 v = (i < N_NODES) ? deg[i] : 0u;
    tmp[t] = v;
    __syncthreads();
    for (int d = 1; d < 256; d <<= 1) {
        u32 u = (t >= d) ? tmp[t - d] : 0u;
        __syncthreads();
        tmp[t] += u;
        __syncthreads();
    }
    if (i < N_NODES) {
        u32 excl = bbase[blockIdx.x] + tmp[t] - v;
        off[i] = excl;
        cursor[i] = excl;
    }
}

// ---------------- permutation pass A: scatter only the 4-B indices ----------------
__global__ __launch_bounds__(256) void perm_build_kernel(const int* __restrict__ ei,
                                                         u32* __restrict__ cursor,
                                                         int* __restrict__ ssrc,
                                                         int* __restrict__ eid) {
    int e = blockIdx.x * 256 + threadIdx.x;
    if (e >= N_EDGES) return;
    int dst = ei[N_EDGES + e];
    u32 pos = atomicAdd(&cursor[dst], 1u);
    ssrc[pos] = ei[e];
    eid[pos] = e;
}

// ---------------- permutation pass B: gather payload (seq write, random read) ----------------
// Sequential full-line ea_perm writes (no RMW allocate); random 128-B ea row
// reads are fully-consumed lines and L3-resident across iterations.
__global__ __launch_bounds__(256) void perm_gather_kernel(const int* __restrict__ eid,
                                                          const float* __restrict__ ea,
                                                          _Float16* __restrict__ ea_perm) {
    int p = blockIdx.x * 256 + threadIdx.x;
    if (p >= N_EDGES) return;
    int e = eid[p];
    const float4* src = (const float4*)(ea + (size_t)e * EDGE_DIM);
    u32 buf[16];
#pragma unroll
    for (int q = 0; q < 8; q++) {
        float4 v = src[q];
        buf[2 * q + 0] = pack_half2(v.x, v.y);
        buf[2 * q + 1] = pack_half2(v.z, v.w);
    }
    uint4* dp = (uint4*)(ea_perm + (size_t)p * EDGE_DIM);
#pragma unroll
    for (int q = 0; q < 4; q++)
        dp[q] = make_uint4(buf[4 * q], buf[4 * q + 1], buf[4 * q + 2], buf[4 * q + 3]);
}

// ---------------- weight precompute ----------------
__global__ __launch_bounds__(256) void wconv_kernel(const float* __restrict__ W1,
                                                    const float* __restrict__ W2,
                                                    const float* __restrict__ We,
                                                    _Float16* __restrict__ w1t,
                                                    _Float16* __restrict__ w2t,
                                                    _Float16* __restrict__ weT) {
    int idx = blockIdx.x * 256 + threadIdx.x;
    if (idx < NUM_LAYERS * 128 * 128) {
        int kk = idx & 127, f = (idx >> 7) & 127, l = idx >> 14;
        int w = kk >> 1;
        int k1 = 32 * (w >> 4) + (w & 15) + ((kk & 1) << 4);
        w1t[idx] = (_Float16)W1[l * 16384 + k1 * 128 + f];
        w2t[idx] = (_Float16)W2[l * 16384 + kk * 128 + f];
    }
    if (idx < NUM_LAYERS * 8 * 64) {
        int lane = idx & 63, c = (idx >> 6) & 7, l = idx >> 9;
        int rg = lane >> 4, li = lane & 15;
        _Float16* dst = weT + (size_t)idx * 8;
#pragma unroll
        for (int j = 0; j < 8; j++)
            dst[j] = (_Float16)We[l * (EDGE_DIM * HIDDEN) + (8 * rg + j) * HIDDEN + c * 16 + li];
    }
}

// ---------------- per-node epilogue: reduce acc + self term + store ----------------
__device__ __forceinline__ void agg_epilogue(int node, const f32x4* __restrict__ acc,
                                             const u32* __restrict__ h16p,
                                             u32* __restrict__ z16b,
                                             int li, int rg, int l) {
    float s[8];
#pragma unroll
    for (int c = 0; c < 8; c++) {
        float v = acc[c][0] + acc[c][1] + acc[c][2] + acc[c][3];
        v += __shfl_xor(v, 16);
        v += __shfl_xor(v, 32);
        s[c] = v;
    }
    float x0 = (rg & 1) ? s[2] : s[0];
    float x1 = (rg & 1) ? s[6] : s[4];
    float va = (rg & 2) ? x1 : x0;
    float y0 = (rg & 1) ? s[3] : s[1];
    float y1 = (rg & 1) ? s[7] : s[5];
    float vb = (rg & 2) ? y1 : y0;
    const u32* hp = h16p + (size_t)node * 64 + li * 4 + 2 * (rg & 1);
    u32 ga = hp[0], gb = hp[1];
    float hva = (rg >= 2) ? (float)as_half2(ga).y : (float)as_half2(ga).x;
    float hvb = (rg >= 2) ? (float)as_half2(gb).y : (float)as_half2(gb).x;
    z16b[(size_t)node * 64 + l] = pack_half2(hva + va, hvb + vb);
}

// ---------------- CSR aggregation via MFMA, cross-node pipelined ----------------
#define AGG_NPW 4
#define AGG_SLOTS ((N_NODES + AGG_NPW - 1) / AGG_NPW)   // 12500
__global__ __launch_bounds__(256) void agg_mfma_kernel(
    const u32* __restrict__ h16p, const _Float16* __restrict__ ea_perm,
    const int* __restrict__ ssrc, const u32* __restrict__ off,
    const _Float16* __restrict__ weT, const float* __restrict__ be,
    u32* __restrict__ z16b) {
    int t = threadIdx.x, l = t & 63, li = l & 15, rg = l >> 4;

    half8 bfrag[8];
    const uint4* wp = (const uint4*)weT;
#pragma unroll
    for (int c = 0; c < 8; c++) {
        union { uint4 u; half8 h; } cv;
        cv.u = wp[c * 64 + l];
        bfrag[c] = cv.h;
    }
    float beC[8];
#pragma unroll
    for (int c = 0; c < 8; c++) beC[c] = be[c * 16 + li];

    const AS4 u32* coff = (const AS4 u32*)(unsigned long long)off;

    int wid = __builtin_amdgcn_readfirstlane(t >> 6);
    int slot = blockIdx.x * 4 + wid;
    if (slot >= AGG_SLOTS) return;
    int na = slot * AGG_NPW;
    int nb = na + AGG_NPW; if (nb > N_NODES) nb = N_NODES;

    f32x4 acc[8];
#pragma unroll
    for (int c = 0; c < 8; c++) acc[c] = (f32x4){0.f, 0.f, 0.f, 0.f};

    int n = na;
    int e0 = (int)coff[n], e1 = (int)coff[n + 1];
    // emit leading empty nodes (acc is zero)
    while (e0 == e1) {
        agg_epilogue(n, acc, h16p, z16b, li, rg, l);
        n++;
        if (n >= nb) return;
        e0 = e1; e1 = (int)coff[n + 1];
    }
    int et = e0;
    // prologue: srcs + A for first tile, then first gathers
    int eb = et + 4 * rg;
    int sv0 = ssrc[(eb + 0 < e1) ? eb + 0 : et];
    int sv1 = ssrc[(eb + 1 < e1) ? eb + 1 : et];
    int sv2 = ssrc[(eb + 2 < e1) ? eb + 2 : et];
    int sv3 = ssrc[(eb + 3 < e1) ? eb + 3 : et];
    uint4 Af = *(const uint4*)(ea_perm + (size_t)(et + li) * 32 + rg * 8);
    uint4 g0 = *(const uint4*)(h16p + (size_t)sv0 * 64 + li * 4);
    uint4 g1 = *(const uint4*)(h16p + (size_t)sv1 * 64 + li * 4);
    uint4 g2 = *(const uint4*)(h16p + (size_t)sv2 * 64 + li * 4);
    uint4 g3 = *(const uint4*)(h16p + (size_t)sv3 * 64 + li * 4);

    while (true) {
        // (1) next-tile determination (scalar pipe)
        int etn = et + 16;
        int n2 = n, et2 = 0, e12 = 0;
        bool more;
        if (etn < e1) { et2 = etn; e12 = e1; more = true; }
        else {
            n2 = n + 1; more = false;
            if (n2 < nb) {
                int a = e1, b = (int)coff[n2 + 1];
                while (a == b && n2 + 1 < nb) { n2++; a = b; b = (int)coff[n2 + 1]; }
                if (a < b) { et2 = a; e12 = b; more = true; }
            }
        }
        // (2) issue next tile's srcs + A early
        int st0 = 0, st1 = 0, st2 = 0, st3 = 0;
        uint4 A2 = Af;
        if (more) {
            int eb2 = et2 + 4 * rg;
            st0 = ssrc[(eb2 + 0 < e12) ? eb2 + 0 : et2];
            st1 = ssrc[(eb2 + 1 < e12) ? eb2 + 1 : et2];
            st2 = ssrc[(eb2 + 2 < e12) ? eb2 + 2 : et2];
            st3 = ssrc[(eb2 + 3 < e12) ? eb2 + 3 : et2];
            A2 = *(const uint4*)(ea_perm + (size_t)(et2 + li) * 32 + rg * 8);
        }
        // (3) MFMA + masked accumulate for current tile
        {
            union { uint4 u; half8 h; } av; av.u = Af;
            int ebase = et + 4 * rg;
            bool v0 = (ebase + 0) < e1, v1 = (ebase + 1) < e1;
            bool v2 = (ebase + 2) < e1, v3 = (ebase + 3) < e1;
#pragma unroll
            for (int q = 0; q < 4; q++) {
                f32x4 cl = (f32x4){beC[q], beC[q], beC[q], beC[q]};
                f32x4 ch = (f32x4){beC[q + 4], beC[q + 4], beC[q + 4], beC[q + 4]};
                f32x4 dl = __builtin_amdgcn_mfma_f32_16x16x32_f16(av.h, bfrag[q], cl, 0, 0, 0);
                f32x4 dh = __builtin_amdgcn_mfma_f32_16x16x32_f16(av.h, bfrag[q + 4], ch, 0, 0, 0);
                u32 w0 = (&g0.x)[q], w1 = (&g1.x)[q], w2 = (&g2.x)[q], w3 = (&g3.x)[q];
                float m;
                m = fmaxf(dl[0] + (float)as_half2(w0).x, 0.f); acc[q][0]     += v0 ? m : 0.f;
                m = fmaxf(dh[0] + (float)as_half2(w0).y, 0.f); acc[q + 4][0] += v0 ? m : 0.f;
                m = fmaxf(dl[1] + (float)as_half2(w1).x, 0.f); acc[q][1]     += v1 ? m : 0.f;
                m = fmaxf(dh[1] + (float)as_half2(w1).y, 0.f); acc[q + 4][1] += v1 ? m : 0.f;
                m = fmaxf(dl[2] + (float)as_half2(w2).x, 0.f); acc[q][2]     += v2 ? m : 0.f;
                m = fmaxf(dh[2] + (float)as_half2(w2).y, 0.f); acc[q + 4][2] += v2 ? m : 0.f;
                m = fmaxf(dl[3] + (float)as_half2(w3).x, 0.f); acc[q][3]     += v3 ? m : 0.f;
                m = fmaxf(dh[3] + (float)as_half2(w3).y, 0.f); acc[q + 4][3] += v3 ? m : 0.f;
            }
        }
        // (4) node boundary: emit epilogue(s), reset acc
        if (etn >= e1) {
            agg_epilogue(n, acc, h16p, z16b, li, rg, l);
#pragma unroll
            for (int c = 0; c < 8; c++) acc[c] = (f32x4){0.f, 0.f, 0.f, 0.f};
            int mend = more ? n2 : nb;
            for (int m = n + 1; m < mend; m++)
                agg_epilogue(m, acc, h16p, z16b, li, rg, l);
        }
        if (!more) break;
        // (5) issue gathers for next tile (consumed next iteration)
        g0 = *(const uint4*)(h16p + (size_t)st0 * 64 + li * 4);
        g1 = *(const uint4*)(h16p + (size_t)st1 * 64 + li * 4);
        g2 = *(const uint4*)(h16p + (size_t)st2 * 64 + li * 4);
        g3 = *(const uint4*)(h16p + (size_t)st3 * 64 + li * 4);
        // (6) advance
        Af = A2; n = n2; et = et2; e1 = e12;
    }
}

// ---------------- fused MLP via MFMA (fp16 in, fp32 accum) ----------------
__global__ __launch_bounds__(256) void mlp_mfma_kernel(
    const u32* __restrict__ z16,
    const _Float16* __restrict__ w1t, const float* __restrict__ b1_,
    const _Float16* __restrict__ w2t, const float* __restrict__ b2_,
    float* __restrict__ z2, float* __restrict__ stats) {
    __shared__ __align__(16) char lds[65536];
    char* zh = lds;            // 32 KB: z tile (k'-order), later h1 tile
    char* wh = lds + 32768;    // 32 KB: W1T, later W2T
    int t = threadIdx.x, l = t & 63, w = t >> 6;
    int li = l & 15, rg = l >> 4;
    int base = blockIdx.x * 128;

    // stage z tile (global uint4 coalesced -> swizzled b128 LDS write)
#pragma unroll
    for (int rep = 0; rep < 8; rep++) {
        int c = t + rep * 256;
        int n = c >> 4, s = c & 15;
        int gn = base + n;
        uint4 v = make_uint4(0u, 0u, 0u, 0u);
        if (gn < N_NODES) v = *(const uint4*)(z16 + (size_t)gn * 64 + s * 4);
        *(uint4*)(zh + n * 256 + ((s ^ (n & 7)) << 4)) = v;
    }
    // stage W1T
#pragma unroll
    for (int rep = 0; rep < 8; rep++) {
        int c = t + rep * 256;
        int f = c >> 4, s = c & 15;
        uint4 v = *(const uint4*)((const char*)w1t + f * 256 + s * 16);
        *(uint4*)(wh + f * 256 + ((s ^ (f & 7)) << 4)) = v;
    }
    __syncthreads();

    int f0 = w * 32 + li;
    int f1 = w * 32 + 16 + li;

    f32x4 acc0[8], acc1[8];
    {
        float bva = b1_[f0], bvb = b1_[f1];
#pragma unroll
        for (int m = 0; m < 8; m++) {
            acc0[m] = (f32x4){bva, bva, bva, bva};
            acc1[m] = (f32x4){bvb, bvb, bvb, bvb};
        }
    }
    // GEMM1: h1 = relu(z @ W1 + b1)
#pragma unroll
    for (int kt = 0; kt < 4; kt++) {
        int s = kt * 4 + rg;
        half8 bf0 = *(const half8*)(wh + f0 * 256 + ((s ^ (f0 & 7)) << 4));
        half8 bf1 = *(const half8*)(wh + f1 * 256 + ((s ^ (f1 & 7)) << 4));
#pragma unroll
        for (int m = 0; m < 8; m++) {
            int n = m * 16 + li;
            half8 af = *(const half8*)(zh + n * 256 + ((s ^ (n & 7)) << 4));
            acc0[m] = __builtin_amdgcn_mfma_f32_16x16x32_f16(af, bf0, acc0[m], 0, 0, 0);
            acc1[m] = __builtin_amdgcn_mfma_f32_16x16x32_f16(af, bf1, acc1[m], 0, 0, 0);
        }
    }
    __syncthreads();   // all GEMM1 reads of zh/wh complete

    // write h1 (relu, fp16) into zh at [node][feat] (identity k for GEMM2)
#pragma unroll
    for (int m = 0; m < 8; m++) {
#pragma unroll
        for (int r = 0; r < 4; r++) {
            int n = m * 16 + rg * 4 + r;
            int s0 = f0 >> 3;
            *(_Float16*)(zh + n * 256 + ((s0 ^ (n & 7)) << 4) + (f0 & 7) * 2) =
                (_Float16)fmaxf(acc0[m][r], 0.f);
            int s1 = f1 >> 3;
            *(_Float16*)(zh + n * 256 + ((s1 ^ (n & 7)) << 4) + (f1 & 7) * 2) =
                (_Float16)fmaxf(acc1[m][r], 0.f);
        }
    }
    // stage W2T into wh
#pragma unroll
    for (int rep = 0; rep < 8; rep++) {
        int c = t + rep * 256;
        int f = c >> 4, s = c & 15;
        uint4 v = *(const uint4*)((const char*)w2t + f * 256 + s * 16);
        *(uint4*)(wh + f * 256 + ((s ^ (f & 7)) << 4)) = v;
    }
    __syncthreads();

    // GEMM2: z2 = h1 @ W2 + b2
    {
        float cva = b2_[f0], cvb = b2_[f1];
#pragma unroll
        for (int m = 0; m < 8; m++) {
            acc0[m] = (f32x4){cva, cva, cva, cva};
            acc1[m] = (f32x4){cvb, cvb, cvb, cvb};
        }
    }
#pragma unroll
    for (int kt = 0; kt < 4; kt++) {
        int s = kt * 4 + rg;
        half8 bf0 = *(const half8*)(wh + f0 * 256 + ((s ^ (f0 & 7)) << 4));
        half8 bf1 = *(const half8*)(wh + f1 * 256 + ((s ^ (f1 & 7)) << 4));
#pragma unroll
        for (int m = 0; m < 8; m++) {
            int n = m * 16 + li;
            half8 af = *(const half8*)(zh + n * 256 + ((s ^ (n & 7)) << 4));
            acc0[m] = __builtin_amdgcn_mfma_f32_16x16x32_f16(af, bf0, acc0[m], 0, 0, 0);
            acc1[m] = __builtin_amdgcn_mfma_f32_16x16x32_f16(af, bf1, acc1[m], 0, 0, 0);
        }
    }

    // epilogue: store z2 (fp32) + fused BN stats
    float s0 = 0.f, q0 = 0.f, s1 = 0.f, q1 = 0.f;
#pragma unroll
    for (int m = 0; m < 8; m++) {
#pragma unroll
        for (int r = 0; r < 4; r++) {
            int gn = base + m * 16 + rg * 4 + r;
            if (gn < N_NODES) {
                float v0 = acc0[m][r], v1 = acc1[m][r];
                z2[(size_t)gn * 128 + f0] = v0;
                z2[(size_t)gn * 128 + f1] = v1;
                s0 += v0; q0 = fmaf(v0, v0, q0);
                s1 += v1; q1 = fmaf(v1, v1, q1);
            }
        }
    }
    s0 += __shfl_xor(s0, 16); s0 += __shfl_xor(s0, 32);
    q0 += __shfl_xor(q0, 16); q0 += __shfl_xor(q0, 32);
    s1 += __shfl_xor(s1, 16); s1 += __shfl_xor(s1, 32);
    q1 += __shfl_xor(q1, 16); q1 += __shfl_xor(q1, 32);
    if (rg == 0) {
        unsafeAtomicAdd(&stats[f0], s0);
        unsafeAtomicAdd(&stats[128 + f0], q0);
        unsafeAtomicAdd(&stats[f1], s1);
        unsafeAtomicAdd(&stats[128 + f1], q1);
    }
}

// ---------------- batchnorm + relu + residual (h16p layout) ----------------
__global__ __launch_bounds__(256) void bn_kernel(
    const float* __restrict__ z2, const float* __restrict__ stats,
    const float* __restrict__ gamma, const float* __restrict__ beta,
    u32* __restrict__ h16, float* __restrict__ out, int write_out) {
    int idx = blockIdx.x * 256 + threadIdx.x;
    if (idx >= N_NODES * 64) return;
    int n = idx >> 6, w = idx & 63;
    int li = w >> 2, q = w & 3;
    int f = q * 16 + li, fh = f + 64;
    const float inv_n = 1.0f / (float)N_NODES;
    float mu_l = stats[f] * inv_n;
    float mu_h = stats[fh] * inv_n;
    float var_l = stats[HIDDEN + f] * inv_n - mu_l * mu_l;
    float var_h = stats[HIDDEN + fh] * inv_n - mu_h * mu_h;
    float inv_l = rsqrtf(var_l + BN_EPS);
    float inv_h = rsqrtf(var_h + BN_EPS);
    float zl = (z2[n * HIDDEN + f]  - mu_l) * inv_l * gamma[f]  + beta[f];
    float zh = (z2[n * HIDDEN + fh] - mu_h) * inv_h * gamma[fh] + beta[fh];
    zl = fmaxf(zl, 0.f);
    zh = fmaxf(zh, 0.f);
    half2_t hh = as_half2(h16[idx]);
    float hn_l = fmaf(RES_SCALE, (float)hh.x, zl);
    float hn_h = fmaf(RES_SCALE, (float)hh.y, zh);
    h16[idx] = pack_half2(hn_l, hn_h);
    if (write_out) {
        out[n * HIDDEN + f]  = hn_l;
        out[n * HIDDEN + fh] = hn_h;
    }
}

extern "C" void kernel_launch(void* const* d_in, const int* in_sizes, int n_in,
                              void* d_out, int out_size, void* d_ws, size_t ws_size,
                              hipStream_t stream) {
    const float* x     = (const float*)d_in[0];
    const int*   ei    = (const int*)d_in[1];
    const float* ea    = (const float*)d_in[2];
    const float* We    = (const float*)d_in[3];
    const float* be    = (const float*)d_in[4];
    const float* W1    = (const float*)d_in[5];
    const float* b1    = (const float*)d_in[6];
    const float* W2    = (const float*)d_in[7];
    const float* b2    = (const float*)d_in[8];
    const float* gamma = (const float*)d_in[9];
    const float* beta  = (const float*)d_in[10];
    float* out = (float*)d_out;

    char* wsp = (char*)d_ws;
    const size_t NH = (size_t)N_NODES * HIDDEN;
    u32*      h16    = (u32*)wsp;      wsp += (size_t)N_NODES * 64 * 4;        // 12.8 MB
    u32*      z16    = (u32*)wsp;      wsp += (size_t)N_NODES * 64 * 4;        // 12.8 MB
    float*    z2     = (float*)wsp;    wsp += NH * 4;                          // 25.6 MB
    _Float16* ea_perm= (_Float16*)wsp; wsp += (size_t)N_EDGES * EDGE_DIM * 2;  // 51.2 MB
    _Float16* w1t    = (_Float16*)wsp; wsp += (size_t)NUM_LAYERS * 128 * 128 * 2;
    _Float16* w2t    = (_Float16*)wsp; wsp += (size_t)NUM_LAYERS * 128 * 128 * 2;
    _Float16* weT    = (_Float16*)wsp; wsp += (size_t)NUM_LAYERS * 4096 * 2;
    float*    statsA = (float*)wsp;    wsp += (size_t)NUM_LAYERS * 256 * 4;
    u32*      deg    = (u32*)wsp;      wsp += (size_t)N_NODES * 4;
    u32*      cursor = (u32*)wsp;      wsp += (size_t)N_NODES * 4;
    int*      ssrc   = (int*)wsp;      wsp += (size_t)N_EDGES * 4;
    int*      eid    = (int*)wsp;      wsp += (size_t)N_EDGES * 4;
    u32*      off    = (u32*)wsp;      wsp += (size_t)(N_NODES + 1) * 4;
    u32*      bsum   = (u32*)wsp;      wsp += (size_t)SCAN_NB * 4;
    u32*      bbase  = (u32*)wsp;      wsp += (size_t)SCAN_NB * 4;

    const int p_blocks  = (N_NODES * 64 + 255) / 256;       // 12500
    const int e_blocks  = (N_EDGES + 255) / 256;            // 3125
    const int m_blocks  = (N_NODES + 127) / 128;            // 391
    const int a_blocks  = (AGG_SLOTS + 3) / 4;              // 3125
    const int w_blocks  = (NUM_LAYERS * 128 * 128 + 255) / 256; // 192

    // CSR build + weight precompute (once per call)
    init_kernel<<<p_blocks, 256, 0, stream>>>(x, h16, deg, statsA);
    hist_kernel<<<e_blocks, 256, 0, stream>>>(ei, deg);
    scan1_kernel<<<SCAN_NB, 256, 0, stream>>>(deg, bsum);
    scan2_kernel<<<1, 256, 0, stream>>>(bsum, bbase, off);
    scan3_kernel<<<SCAN_NB, 256, 0, stream>>>(deg, bbase, off, cursor);
    perm_build_kernel<<<e_blocks, 256, 0, stream>>>(ei, cursor, ssrc, eid);
    perm_gather_kernel<<<e_blocks, 256, 0, stream>>>(eid, ea, ea_perm);
    wconv_kernel<<<w_blocks, 256, 0, stream>>>(W1, W2, We, w1t, w2t, weT);

    for (int l = 0; l < NUM_LAYERS; l++) {
        agg_mfma_kernel<<<a_blocks, 256, 0, stream>>>(
            h16, ea_perm, ssrc, off,
            weT + (size_t)l * 4096, be + (size_t)l * HIDDEN, z16);
        mlp_mfma_kernel<<<m_blocks, 256, 0, stream>>>(
            z16, w1t + (size_t)l * 16384, b1 + (size_t)l * HIDDEN,
            w2t + (size_t)l * 16384, b2 + (size_t)l * HIDDEN,
            z2, statsA + (size_t)l * 256);
        bn_kernel<<<p_blocks, 256, 0, stream>>>(
            z2, statsA + (size_t)l * 256, gamma + (size_t)l * HIDDEN, beta + (size_t)l * HIDDEN,
            h16, out, (l == NUM_LAYERS - 1) ? 1 : 0);
    }
}

// Round 11
// 623.820 us; speedup vs baseline: 1.0121x; 1.0121x over previous
//
#include <hip/hip_runtime.h>
#include <hip/hip_bf16.h>

#define N_NODES   50000
#define N_EDGES   800000
#define IN_DIM    128
#define EDGE_DIM  32
#define HIDDEN    128
#define NUM_LAYERS 3
#define BN_EPS    1e-5f
#define RES_SCALE 0.1f

typedef unsigned int   u32;
typedef unsigned short u16;
typedef _Float16 half2_t __attribute__((ext_vector_type(2)));
typedef _Float16 half8 __attribute__((ext_vector_type(8)));
typedef unsigned int u32x4 __attribute__((ext_vector_type(4)));
typedef float f32x4 __attribute__((ext_vector_type(4)));

#define AS4 __attribute__((address_space(4)))

__device__ __forceinline__ half2_t as_half2(u32 v) {
    union { u32 u; half2_t h; } c; c.u = v; return c.h;
}
__device__ __forceinline__ u32 pack_half2(float a, float b) {
    union { u32 u; half2_t h; } c;
    c.h.x = (_Float16)a; c.h.y = (_Float16)b; return c.u;
}

// ---------------- pack x -> h16p ; zero deg ; zero stats ----------------
// h16p layout: word w = li*4+q (li=0..15, q=0..3) holds fp16 pair
// (feat q*16+li, feat 64+q*16+li) -> agg gathers are one dwordx4 per lane.
__global__ __launch_bounds__(256) void init_kernel(const float* __restrict__ x,
                                                   u32* __restrict__ h16,
                                                   u32* __restrict__ deg,
                                                   float* __restrict__ statsAll) {
    int idx = blockIdx.x * 256 + threadIdx.x;
    if (idx < N_NODES * 64) {
        int n = idx >> 6, w = idx & 63;
        int li = w >> 2, q = w & 3;
        int f = q * 16 + li;
        h16[idx] = pack_half2(x[n * HIDDEN + f], x[n * HIDDEN + 64 + f]);
    }
    if (idx < N_NODES) deg[idx] = 0u;
    if (idx < NUM_LAYERS * 256) statsAll[idx] = 0.f;
}

// ---------------- degree histogram ----------------
__global__ __launch_bounds__(256) void hist_kernel(const int* __restrict__ ei,
                                                   u32* __restrict__ deg) {
    int e = blockIdx.x * 256 + threadIdx.x;
    if (e < N_EDGES) atomicAdd(&deg[ei[N_EDGES + e]], 1u);
}

// ---------------- multi-block exclusive scan (3 passes) ----------------
#define SCAN_NB ((N_NODES + 255) / 256)   // 196

__global__ __launch_bounds__(256) void scan1_kernel(const u32* __restrict__ deg,
                                                    u32* __restrict__ bsum) {
    int i = blockIdx.x * 256 + threadIdx.x;
    u32 v = (i < N_NODES) ? deg[i] : 0u;
    v += __shfl_down(v, 32, 64);
    v += __shfl_down(v, 16, 64);
    v += __shfl_down(v, 8, 64);
    v += __shfl_down(v, 4, 64);
    v += __shfl_down(v, 2, 64);
    v += __shfl_down(v, 1, 64);
    __shared__ u32 ws[4];
    if ((threadIdx.x & 63) == 0) ws[threadIdx.x >> 6] = v;
    __syncthreads();
    if (threadIdx.x == 0) bsum[blockIdx.x] = ws[0] + ws[1] + ws[2] + ws[3];
}

__global__ __launch_bounds__(256) void scan2_kernel(const u32* __restrict__ bsum,
                                                    u32* __restrict__ bbase,
                                                    u32* __restrict__ off) {
    __shared__ u32 tmp[256];
    int t = threadIdx.x;
    u32 v = (t < SCAN_NB) ? bsum[t] : 0u;
    tmp[t] = v;
    __syncthreads();
    for (int d = 1; d < 256; d <<= 1) {
        u32 u = (t >= d) ? tmp[t - d] : 0u;
        __syncthreads();
        tmp[t] += u;
        __syncthreads();
    }
    if (t < SCAN_NB) bbase[t] = (t == 0) ? 0u : tmp[t - 1];
    if (t == 255) off[N_NODES] = tmp[255];   // grand total
}

__global__ __launch_bounds__(256) void scan3_kernel(const u32* __restrict__ deg,
                                                    const u32* __restrict__ bbase,
                                                    u32* __restrict__ off,
                                                    u32* __restrict__ cursor) {
    __shared__ u32 tmp[256];
    int t = threadIdx.x;
    int i = blockIdx.x * 256 + t;
    u32 v = (i < N_NODES) ? deg[i] : 0u;
    tmp[t] = v;
    __syncthreads();
    for (int d = 1; d < 256; d <<= 1) {
        u32 u = (t >= d) ? tmp[t - d] : 0u;
        __syncthreads();
        tmp[t] += u;
        __syncthreads();
    }
    if (i < N_NODES) {
        u32 excl = bbase[blockIdx.x] + tmp[t] - v;
        off[i] = excl;
        cursor[i] = excl;
    }
}

// ---------------- scatter edges into CSR order + permute ea (f16) ----------------
__global__ __launch_bounds__(256) void scatter_kernel(const int* __restrict__ ei,
                                                      u32* __restrict__ cursor,
                                                      int* __restrict__ ssrc,
                                                      const float* __restrict__ ea,
                                                      _Float16* __restrict__ ea_perm) {
    int e = blockIdx.x * 256 + threadIdx.x;
    if (e >= N_EDGES) return;
    int dst = ei[N_EDGES + e];
    u32 pos = atomicAdd(&cursor[dst], 1u);
    ssrc[pos] = ei[e];
    const float4* src = (const float4*)(ea + (size_t)e * EDGE_DIM);
    u32 buf[16];
#pragma unroll
    for (int q = 0; q < 8; q++) {
        float4 v = src[q];
        buf[2 * q + 0] = pack_half2(v.x, v.y);
        buf[2 * q + 1] = pack_half2(v.z, v.w);
    }
    uint4* dp = (uint4*)(ea_perm + (size_t)pos * EDGE_DIM);
#pragma unroll
    for (int q = 0; q < 4; q++)
        dp[q] = make_uint4(buf[4 * q], buf[4 * q + 1], buf[4 * q + 2], buf[4 * q + 3]);
}

// ---------------- weight precompute ----------------
__global__ __launch_bounds__(256) void wconv_kernel(const float* __restrict__ W1,
                                                    const float* __restrict__ W2,
                                                    const float* __restrict__ We,
                                                    _Float16* __restrict__ w1t,
                                                    _Float16* __restrict__ w2t,
                                                    _Float16* __restrict__ weT) {
    int idx = blockIdx.x * 256 + threadIdx.x;
    if (idx < NUM_LAYERS * 128 * 128) {
        int kk = idx & 127, f = (idx >> 7) & 127, l = idx >> 14;
        int w = kk >> 1;
        int k1 = 32 * (w >> 4) + (w & 15) + ((kk & 1) << 4);
        w1t[idx] = (_Float16)W1[l * 16384 + k1 * 128 + f];
        w2t[idx] = (_Float16)W2[l * 16384 + kk * 128 + f];
    }
    if (idx < NUM_LAYERS * 8 * 64) {
        int lane = idx & 63, c = (idx >> 6) & 7, l = idx >> 9;
        int rg = lane >> 4, li = lane & 15;
        _Float16* dst = weT + (size_t)idx * 8;
#pragma unroll
        for (int j = 0; j < 8; j++)
            dst[j] = (_Float16)We[l * (EDGE_DIM * HIDDEN) + (8 * rg + j) * HIDDEN + c * 16 + li];
    }
}

// ---------------- per-node epilogue: reduce acc + self term + store ----------------
__device__ __forceinline__ void agg_epilogue(int node, const f32x4* __restrict__ acc,
                                             const u32* __restrict__ h16p,
                                             u32* __restrict__ z16b,
                                             int li, int rg, int l) {
    float s[8];
#pragma unroll
    for (int c = 0; c < 8; c++) {
        float v = acc[c][0] + acc[c][1] + acc[c][2] + acc[c][3];
        v += __shfl_xor(v, 16);
        v += __shfl_xor(v, 32);
        s[c] = v;
    }
    float x0 = (rg & 1) ? s[2] : s[0];
    float x1 = (rg & 1) ? s[6] : s[4];
    float va = (rg & 2) ? x1 : x0;
    float y0 = (rg & 1) ? s[3] : s[1];
    float y1 = (rg & 1) ? s[7] : s[5];
    float vb = (rg & 2) ? y1 : y0;
    const u32* hp = h16p + (size_t)node * 64 + li * 4 + 2 * (rg & 1);
    u32 ga = hp[0], gb = hp[1];
    float hva = (rg >= 2) ? (float)as_half2(ga).y : (float)as_half2(ga).x;
    float hvb = (rg >= 2) ? (float)as_half2(gb).y : (float)as_half2(gb).x;
    z16b[(size_t)node * 64 + l] = pack_half2(hva + va, hvb + vb);
}

// ---------------- CSR aggregation via MFMA, cross-node pipelined ----------------
// NPW=16: 3125 waves (782 blocks, ~3 blocks/CU) -> whole grid resident from
// t=0 (no sequential occupancy rounds, no tail), ~18 tiles/wave gives the
// 1-ahead prefetch a long runway and amortizes prologue/epilogue 4x.
#define AGG_NPW 16
#define AGG_SLOTS ((N_NODES + AGG_NPW - 1) / AGG_NPW)   // 3125
__global__ __launch_bounds__(256) void agg_mfma_kernel(
    const u32* __restrict__ h16p, const _Float16* __restrict__ ea_perm,
    const int* __restrict__ ssrc, const u32* __restrict__ off,
    const _Float16* __restrict__ weT, const float* __restrict__ be,
    u32* __restrict__ z16b) {
    int t = threadIdx.x, l = t & 63, li = l & 15, rg = l >> 4;

    half8 bfrag[8];
    const uint4* wp = (const uint4*)weT;
#pragma unroll
    for (int c = 0; c < 8; c++) {
        union { uint4 u; half8 h; } cv;
        cv.u = wp[c * 64 + l];
        bfrag[c] = cv.h;
    }
    float beC[8];
#pragma unroll
    for (int c = 0; c < 8; c++) beC[c] = be[c * 16 + li];

    const AS4 u32* coff = (const AS4 u32*)(unsigned long long)off;

    int wid = __builtin_amdgcn_readfirstlane(t >> 6);
    int slot = blockIdx.x * 4 + wid;
    if (slot >= AGG_SLOTS) return;
    int na = slot * AGG_NPW;
    int nb = na + AGG_NPW; if (nb > N_NODES) nb = N_NODES;

    f32x4 acc[8];
#pragma unroll
    for (int c = 0; c < 8; c++) acc[c] = (f32x4){0.f, 0.f, 0.f, 0.f};

    int n = na;
    int e0 = (int)coff[n], e1 = (int)coff[n + 1];
    // emit leading empty nodes (acc is zero)
    while (e0 == e1) {
        agg_epilogue(n, acc, h16p, z16b, li, rg, l);
        n++;
        if (n >= nb) return;
        e0 = e1; e1 = (int)coff[n + 1];
    }
    int et = e0;
    // prologue: srcs + A for first tile, then first gathers
    int eb = et + 4 * rg;
    int sv0 = ssrc[(eb + 0 < e1) ? eb + 0 : et];
    int sv1 = ssrc[(eb + 1 < e1) ? eb + 1 : et];
    int sv2 = ssrc[(eb + 2 < e1) ? eb + 2 : et];
    int sv3 = ssrc[(eb + 3 < e1) ? eb + 3 : et];
    uint4 Af = *(const uint4*)(ea_perm + (size_t)(et + li) * 32 + rg * 8);
    uint4 g0 = *(const uint4*)(h16p + (size_t)sv0 * 64 + li * 4);
    uint4 g1 = *(const uint4*)(h16p + (size_t)sv1 * 64 + li * 4);
    uint4 g2 = *(const uint4*)(h16p + (size_t)sv2 * 64 + li * 4);
    uint4 g3 = *(const uint4*)(h16p + (size_t)sv3 * 64 + li * 4);

    while (true) {
        // (1) next-tile determination (scalar pipe)
        int etn = et + 16;
        int n2 = n, et2 = 0, e12 = 0;
        bool more;
        if (etn < e1) { et2 = etn; e12 = e1; more = true; }
        else {
            n2 = n + 1; more = false;
            if (n2 < nb) {
                int a = e1, b = (int)coff[n2 + 1];
                while (a == b && n2 + 1 < nb) { n2++; a = b; b = (int)coff[n2 + 1]; }
                if (a < b) { et2 = a; e12 = b; more = true; }
            }
        }
        // (2) issue next tile's srcs + A early
        int st0 = 0, st1 = 0, st2 = 0, st3 = 0;
        uint4 A2 = Af;
        if (more) {
            int eb2 = et2 + 4 * rg;
            st0 = ssrc[(eb2 + 0 < e12) ? eb2 + 0 : et2];
            st1 = ssrc[(eb2 + 1 < e12) ? eb2 + 1 : et2];
            st2 = ssrc[(eb2 + 2 < e12) ? eb2 + 2 : et2];
            st3 = ssrc[(eb2 + 3 < e12) ? eb2 + 3 : et2];
            A2 = *(const uint4*)(ea_perm + (size_t)(et2 + li) * 32 + rg * 8);
        }
        // (3) MFMA + masked accumulate for current tile
        {
            union { uint4 u; half8 h; } av; av.u = Af;
            int ebase = et + 4 * rg;
            bool v0 = (ebase + 0) < e1, v1 = (ebase + 1) < e1;
            bool v2 = (ebase + 2) < e1, v3 = (ebase + 3) < e1;
#pragma unroll
            for (int q = 0; q < 4; q++) {
                f32x4 cl = (f32x4){beC[q], beC[q], beC[q], beC[q]};
                f32x4 ch = (f32x4){beC[q + 4], beC[q + 4], beC[q + 4], beC[q + 4]};
                f32x4 dl = __builtin_amdgcn_mfma_f32_16x16x32_f16(av.h, bfrag[q], cl, 0, 0, 0);
                f32x4 dh = __builtin_amdgcn_mfma_f32_16x16x32_f16(av.h, bfrag[q + 4], ch, 0, 0, 0);
                u32 w0 = (&g0.x)[q], w1 = (&g1.x)[q], w2 = (&g2.x)[q], w3 = (&g3.x)[q];
                float m;
                m = fmaxf(dl[0] + (float)as_half2(w0).x, 0.f); acc[q][0]     += v0 ? m : 0.f;
                m = fmaxf(dh[0] + (float)as_half2(w0).y, 0.f); acc[q + 4][0] += v0 ? m : 0.f;
                m = fmaxf(dl[1] + (float)as_half2(w1).x, 0.f); acc[q][1]     += v1 ? m : 0.f;
                m = fmaxf(dh[1] + (float)as_half2(w1).y, 0.f); acc[q + 4][1] += v1 ? m : 0.f;
                m = fmaxf(dl[2] + (float)as_half2(w2).x, 0.f); acc[q][2]     += v2 ? m : 0.f;
                m = fmaxf(dh[2] + (float)as_half2(w2).y, 0.f); acc[q + 4][2] += v2 ? m : 0.f;
                m = fmaxf(dl[3] + (float)as_half2(w3).x, 0.f); acc[q][3]     += v3 ? m : 0.f;
                m = fmaxf(dh[3] + (float)as_half2(w3).y, 0.f); acc[q + 4][3] += v3 ? m : 0.f;
            }
        }
        // (4) node boundary: emit epilogue(s), reset acc
        if (etn >= e1) {
            agg_epilogue(n, acc, h16p, z16b, li, rg, l);
#pragma unroll
            for (int c = 0; c < 8; c++) acc[c] = (f32x4){0.f, 0.f, 0.f, 0.f};
            int mend = more ? n2 : nb;
            for (int m = n + 1; m < mend; m++)
                agg_epilogue(m, acc, h16p, z16b, li, rg, l);
        }
        if (!more) break;
        // (5) issue gathers for next tile (consumed next iteration)
        g0 = *(const uint4*)(h16p + (size_t)st0 * 64 + li * 4);
        g1 = *(const uint4*)(h16p + (size_t)st1 * 64 + li * 4);
        g2 = *(const uint4*)(h16p + (size_t)st2 * 64 + li * 4);
        g3 = *(const uint4*)(h16p + (size_t)st3 * 64 + li * 4);
        // (6) advance
        Af = A2; n = n2; et = et2; e1 = e12;
    }
}

// ---------------- fused MLP via MFMA (fp16 in, fp32 accum) ----------------
__global__ __launch_bounds__(256) void mlp_mfma_kernel(
    const u32* __restrict__ z16,
    const _Float16* __restrict__ w1t, const float* __restrict__ b1_,
    const _Float16* __restrict__ w2t, const float* __restrict__ b2_,
    float* __restrict__ z2, float* __restrict__ stats) {
    __shared__ __align__(16) char lds[65536];
    char* zh = lds;            // 32 KB: z tile (k'-order), later h1 tile
    char* wh = lds + 32768;    // 32 KB: W1T, later W2T
    int t = threadIdx.x, l = t & 63, w = t >> 6;
    int li = l & 15, rg = l >> 4;
    int base = blockIdx.x * 128;

    // stage z tile (global uint4 coalesced -> swizzled b128 LDS write)
#pragma unroll
    for (int rep = 0; rep < 8; rep++) {
        int c = t + rep * 256;
        int n = c >> 4, s = c & 15;
        int gn = base + n;
        uint4 v = make_uint4(0u, 0u, 0u, 0u);
        if (gn < N_NODES) v = *(const uint4*)(z16 + (size_t)gn * 64 + s * 4);
        *(uint4*)(zh + n * 256 + ((s ^ (n & 7)) << 4)) = v;
    }
    // stage W1T
#pragma unroll
    for (int rep = 0; rep < 8; rep++) {
        int c = t + rep * 256;
        int f = c >> 4, s = c & 15;
        uint4 v = *(const uint4*)((const char*)w1t + f * 256 + s * 16);
        *(uint4*)(wh + f * 256 + ((s ^ (f & 7)) << 4)) = v;
    }
    __syncthreads();

    int f0 = w * 32 + li;
    int f1 = w * 32 + 16 + li;

    f32x4 acc0[8], acc1[8];
    {
        float bva = b1_[f0], bvb = b1_[f1];
#pragma unroll
        for (int m = 0; m < 8; m++) {
            acc0[m] = (f32x4){bva, bva, bva, bva};
            acc1[m] = (f32x4){bvb, bvb, bvb, bvb};
        }
    }
    // GEMM1: h1 = relu(z @ W1 + b1)
#pragma unroll
    for (int kt = 0; kt < 4; kt++) {
        int s = kt * 4 + rg;
        half8 bf0 = *(const half8*)(wh + f0 * 256 + ((s ^ (f0 & 7)) << 4));
        half8 bf1 = *(const half8*)(wh + f1 * 256 + ((s ^ (f1 & 7)) << 4));
#pragma unroll
        for (int m = 0; m < 8; m++) {
            int n = m * 16 + li;
            half8 af = *(const half8*)(zh + n * 256 + ((s ^ (n & 7)) << 4));
            acc0[m] = __builtin_amdgcn_mfma_f32_16x16x32_f16(af, bf0, acc0[m], 0, 0, 0);
            acc1[m] = __builtin_amdgcn_mfma_f32_16x16x32_f16(af, bf1, acc1[m], 0, 0, 0);
        }
    }
    __syncthreads();   // all GEMM1 reads of zh/wh complete

    // write h1 (relu, fp16) into zh at [node][feat] (identity k for GEMM2)
#pragma unroll
    for (int m = 0; m < 8; m++) {
#pragma unroll
        for (int r = 0; r < 4; r++) {
            int n = m * 16 + rg * 4 + r;
            int s0 = f0 >> 3;
            *(_Float16*)(zh + n * 256 + ((s0 ^ (n & 7)) << 4) + (f0 & 7) * 2) =
                (_Float16)fmaxf(acc0[m][r], 0.f);
            int s1 = f1 >> 3;
            *(_Float16*)(zh + n * 256 + ((s1 ^ (n & 7)) << 4) + (f1 & 7) * 2) =
                (_Float16)fmaxf(acc1[m][r], 0.f);
        }
    }
    // stage W2T into wh
#pragma unroll
    for (int rep = 0; rep < 8; rep++) {
        int c = t + rep * 256;
        int f = c >> 4, s = c & 15;
        uint4 v = *(const uint4*)((const char*)w2t + f * 256 + s * 16);
        *(uint4*)(wh + f * 256 + ((s ^ (f & 7)) << 4)) = v;
    }
    __syncthreads();

    // GEMM2: z2 = h1 @ W2 + b2
    {
        float cva = b2_[f0], cvb = b2_[f1];
#pragma unroll
        for (int m = 0; m < 8; m++) {
            acc0[m] = (f32x4){cva, cva, cva, cva};
            acc1[m] = (f32x4){cvb, cvb, cvb, cvb};
        }
    }
#pragma unroll
    for (int kt = 0; kt < 4; kt++) {
        int s = kt * 4 + rg;
        half8 bf0 = *(const half8*)(wh + f0 * 256 + ((s ^ (f0 & 7)) << 4));
        half8 bf1 = *(const half8*)(wh + f1 * 256 + ((s ^ (f1 & 7)) << 4));
#pragma unroll
        for (int m = 0; m < 8; m++) {
            int n = m * 16 + li;
            half8 af = *(const half8*)(zh + n * 256 + ((s ^ (n & 7)) << 4));
            acc0[m] = __builtin_amdgcn_mfma_f32_16x16x32_f16(af, bf0, acc0[m], 0, 0, 0);
            acc1[m] = __builtin_amdgcn_mfma_f32_16x16x32_f16(af, bf1, acc1[m], 0, 0, 0);
        }
    }

    // epilogue: store z2 (fp32) + fused BN stats
    float s0 = 0.f, q0 = 0.f, s1 = 0.f, q1 = 0.f;
#pragma unroll
    for (int m = 0; m < 8; m++) {
#pragma unroll
        for (int r = 0; r < 4; r++) {
            int gn = base + m * 16 + rg * 4 + r;
            if (gn < N_NODES) {
                float v0 = acc0[m][r], v1 = acc1[m][r];
                z2[(size_t)gn * 128 + f0] = v0;
                z2[(size_t)gn * 128 + f1] = v1;
                s0 += v0; q0 = fmaf(v0, v0, q0);
                s1 += v1; q1 = fmaf(v1, v1, q1);
            }
        }
    }
    s0 += __shfl_xor(s0, 16); s0 += __shfl_xor(s0, 32);
    q0 += __shfl_xor(q0, 16); q0 += __shfl_xor(q0, 32);
    s1 += __shfl_xor(s1, 16); s1 += __shfl_xor(s1, 32);
    q1 += __shfl_xor(q1, 16); q1 += __shfl_xor(q1, 32);
    if (rg == 0) {
        unsafeAtomicAdd(&stats[f0], s0);
        unsafeAtomicAdd(&stats[128 + f0], q0);
        unsafeAtomicAdd(&stats[f1], s1);
        unsafeAtomicAdd(&stats[128 + f1], q1);
    }
}

// ---------------- batchnorm + relu + residual (h16p layout) ----------------
__global__ __launch_bounds__(256) void bn_kernel(
    const float* __restrict__ z2, const float* __restrict__ stats,
    const float* __restrict__ gamma, const float* __restrict__ beta,
    u32* __restrict__ h16, float* __restrict__ out, int write_out) {
    int idx = blockIdx.x * 256 + threadIdx.x;
    if (idx >= N_NODES * 64) return;
    int n = idx >> 6, w = idx & 63;
    int li = w >> 2, q = w & 3;
    int f = q * 16 + li, fh = f + 64;
    const float inv_n = 1.0f / (float)N_NODES;
    float mu_l = stats[f] * inv_n;
    float mu_h = stats[fh] * inv_n;
    float var_l = stats[HIDDEN + f] * inv_n - mu_l * mu_l;
    float var_h = stats[HIDDEN + fh] * inv_n - mu_h * mu_h;
    float inv_l = rsqrtf(var_l + BN_EPS);
    float inv_h = rsqrtf(var_h + BN_EPS);
    float zl = (z2[n * HIDDEN + f]  - mu_l) * inv_l * gamma[f]  + beta[f];
    float zh = (z2[n * HIDDEN + fh] - mu_h) * inv_h * gamma[fh] + beta[fh];
    zl = fmaxf(zl, 0.f);
    zh = fmaxf(zh, 0.f);
    half2_t hh = as_half2(h16[idx]);
    float hn_l = fmaf(RES_SCALE, (float)hh.x, zl);
    float hn_h = fmaf(RES_SCALE, (float)hh.y, zh);
    h16[idx] = pack_half2(hn_l, hn_h);
    if (write_out) {
        out[n * HIDDEN + f]  = hn_l;
        out[n * HIDDEN + fh] = hn_h;
    }
}

extern "C" void kernel_launch(void* const* d_in, const int* in_sizes, int n_in,
                              void* d_out, int out_size, void* d_ws, size_t ws_size,
                              hipStream_t stream) {
    const float* x     = (const float*)d_in[0];
    const int*   ei    = (const int*)d_in[1];
    const float* ea    = (const float*)d_in[2];
    const float* We    = (const float*)d_in[3];
    const float* be    = (const float*)d_in[4];
    const float* W1    = (const float*)d_in[5];
    const float* b1    = (const float*)d_in[6];
    const float* W2    = (const float*)d_in[7];
    const float* b2    = (const float*)d_in[8];
    const float* gamma = (const float*)d_in[9];
    const float* beta  = (const float*)d_in[10];
    float* out = (float*)d_out;

    char* wsp = (char*)d_ws;
    const size_t NH = (size_t)N_NODES * HIDDEN;
    u32*      h16    = (u32*)wsp;      wsp += (size_t)N_NODES * 64 * 4;        // 12.8 MB
    u32*      z16    = (u32*)wsp;      wsp += (size_t)N_NODES * 64 * 4;        // 12.8 MB
    float*    z2     = (float*)wsp;    wsp += NH * 4;                          // 25.6 MB
    _Float16* ea_perm= (_Float16*)wsp; wsp += (size_t)N_EDGES * EDGE_DIM * 2;  // 51.2 MB
    _Float16* w1t    = (_Float16*)wsp; wsp += (size_t)NUM_LAYERS * 128 * 128 * 2;
    _Float16* w2t    = (_Float16*)wsp; wsp += (size_t)NUM_LAYERS * 128 * 128 * 2;
    _Float16* weT    = (_Float16*)wsp; wsp += (size_t)NUM_LAYERS * 4096 * 2;
    float*    statsA = (float*)wsp;    wsp += (size_t)NUM_LAYERS * 256 * 4;
    u32*      deg    = (u32*)wsp;      wsp += (size_t)N_NODES * 4;
    u32*      cursor = (u32*)wsp;      wsp += (size_t)N_NODES * 4;
    int*      ssrc   = (int*)wsp;      wsp += (size_t)N_EDGES * 4;
    u32*      off    = (u32*)wsp;      wsp += (size_t)(N_NODES + 1) * 4;
    u32*      bsum   = (u32*)wsp;      wsp += (size_t)SCAN_NB * 4;
    u32*      bbase  = (u32*)wsp;      wsp += (size_t)SCAN_NB * 4;

    const int p_blocks  = (N_NODES * 64 + 255) / 256;       // 12500
    const int e_blocks  = (N_EDGES + 255) / 256;            // 3125
    const int m_blocks  = (N_NODES + 127) / 128;            // 391
    const int a_blocks  = (AGG_SLOTS + 3) / 4;              // 782
    const int w_blocks  = (NUM_LAYERS * 128 * 128 + 255) / 256; // 192

    // CSR build + weight precompute (once per call)
    init_kernel<<<p_blocks, 256, 0, stream>>>(x, h16, deg, statsA);
    hist_kernel<<<e_blocks, 256, 0, stream>>>(ei, deg);
    scan1_kernel<<<SCAN_NB, 256, 0, stream>>>(deg, bsum);
    scan2_kernel<<<1, 256, 0, stream>>>(bsum, bbase, off);
    scan3_kernel<<<SCAN_NB, 256, 0, stream>>>(deg, bbase, off, cursor);
    scatter_kernel<<<e_blocks, 256, 0, stream>>>(ei, cursor, ssrc, ea, ea_perm);
    wconv_kernel<<<w_blocks, 256, 0, stream>>>(W1, W2, We, w1t, w2t, weT);

    for (int l = 0; l < NUM_LAYERS; l++) {
        agg_mfma_kernel<<<a_blocks, 256, 0, stream>>>(
            h16, ea_perm, ssrc, off,
            weT + (size_t)l * 4096, be + (size_t)l * HIDDEN, z16);
        mlp_mfma_kernel<<<m_blocks, 256, 0, stream>>>(
            z16, w1t + (size_t)l * 16384, b1 + (size_t)l * HIDDEN,
            w2t + (size_t)l * 16384, b2 + (size_t)l * HIDDEN,
            z2, statsA + (size_t)l * 256);
        bn_kernel<<<p_blocks, 256, 0, stream>>>(
            z2, statsA + (size_t)l * 256, gamma + (size_t)l * HIDDEN, beta + (size_t)l * HIDDEN,
            h16, out, (l == NUM_LAYERS - 1) ? 1 : 0);
    }
}

// Round 12
// 577.704 us; speedup vs baseline: 1.0929x; 1.0798x over previous
//
#include <hip/hip_runtime.h>
#include <hip/hip_bf16.h>

#define N_NODES   50000
#define N_EDGES   800000
#define IN_DIM    128
#define EDGE_DIM  32
#define HIDDEN    128
#define NUM_LAYERS 3
#define BN_EPS    1e-5f
#define RES_SCALE 0.1f

typedef unsigned int   u32;
typedef unsigned short u16;
typedef _Float16 half2_t __attribute__((ext_vector_type(2)));
typedef _Float16 half8 __attribute__((ext_vector_type(8)));
typedef unsigned int u32x4 __attribute__((ext_vector_type(4)));
typedef float f32x4 __attribute__((ext_vector_type(4)));

#define AS4 __attribute__((address_space(4)))

__device__ __forceinline__ half2_t as_half2(u32 v) {
    union { u32 u; half2_t h; } c; c.u = v; return c.h;
}
__device__ __forceinline__ u32 pack_half2(float a, float b) {
    union { u32 u; half2_t h; } c;
    c.h.x = (_Float16)a; c.h.y = (_Float16)b; return c.u;
}

// ---------------- pack x -> h16p ; zero deg ; zero stats ----------------
// h16p layout: word w = li*4+q (li=0..15, q=0..3) holds fp16 pair
// (feat q*16+li, feat 64+q*16+li) -> agg gathers are one dwordx4 per lane.
__global__ __launch_bounds__(256) void init_kernel(const float* __restrict__ x,
                                                   u32* __restrict__ h16,
                                                   u32* __restrict__ deg,
                                                   float* __restrict__ statsAll) {
    int idx = blockIdx.x * 256 + threadIdx.x;
    if (idx < N_NODES * 64) {
        int n = idx >> 6, w = idx & 63;
        int li = w >> 2, q = w & 3;
        int f = q * 16 + li;
        h16[idx] = pack_half2(x[n * HIDDEN + f], x[n * HIDDEN + 64 + f]);
    }
    if (idx < N_NODES) deg[idx] = 0u;
    if (idx < NUM_LAYERS * 256) statsAll[idx] = 0.f;
}

// ---------------- degree histogram ----------------
__global__ __launch_bounds__(256) void hist_kernel(const int* __restrict__ ei,
                                                   u32* __restrict__ deg) {
    int e = blockIdx.x * 256 + threadIdx.x;
    if (e < N_EDGES) atomicAdd(&deg[ei[N_EDGES + e]], 1u);
}

// ---------------- multi-block exclusive scan (3 passes) ----------------
#define SCAN_NB ((N_NODES + 255) / 256)   // 196

__global__ __launch_bounds__(256) void scan1_kernel(const u32* __restrict__ deg,
                                                    u32* __restrict__ bsum) {
    int i = blockIdx.x * 256 + threadIdx.x;
    u32 v = (i < N_NODES) ? deg[i] : 0u;
    v += __shfl_down(v, 32, 64);
    v += __shfl_down(v, 16, 64);
    v += __shfl_down(v, 8, 64);
    v += __shfl_down(v, 4, 64);
    v += __shfl_down(v, 2, 64);
    v += __shfl_down(v, 1, 64);
    __shared__ u32 ws[4];
    if ((threadIdx.x & 63) == 0) ws[threadIdx.x >> 6] = v;
    __syncthreads();
    if (threadIdx.x == 0) bsum[blockIdx.x] = ws[0] + ws[1] + ws[2] + ws[3];
}

__global__ __launch_bounds__(256) void scan2_kernel(const u32* __restrict__ bsum,
                                                    u32* __restrict__ bbase,
                                                    u32* __restrict__ off) {
    __shared__ u32 tmp[256];
    int t = threadIdx.x;
    u32 v = (t < SCAN_NB) ? bsum[t] : 0u;
    tmp[t] = v;
    __syncthreads();
    for (int d = 1; d < 256; d <<= 1) {
        u32 u = (t >= d) ? tmp[t - d] : 0u;
        __syncthreads();
        tmp[t] += u;
        __syncthreads();
    }
    if (t < SCAN_NB) bbase[t] = (t == 0) ? 0u : tmp[t - 1];
    if (t == 255) off[N_NODES] = tmp[255];   // grand total
}

__global__ __launch_bounds__(256) void scan3_kernel(const u32* __restrict__ deg,
                                                    const u32* __restrict__ bbase,
                                                    u32* __restrict__ off,
                                                    u32* __restrict__ cursor) {
    __shared__ u32 tmp[256];
    int t = threadIdx.x;
    int i = blockIdx.x * 256 + t;
    u32 v = (i < N_NODES) ? deg[i] : 0u;
    tmp[t] = v;
    __syncthreads();
    for (int d = 1; d < 256; d <<= 1) {
        u32 u = (t >= d) ? tmp[t - d] : 0u;
        __syncthreads();
        tmp[t] += u;
        __syncthreads();
    }
    if (i < N_NODES) {
        u32 excl = bbase[blockIdx.x] + tmp[t] - v;
        off[i] = excl;
        cursor[i] = excl;
    }
}

// ---------------- scatter edges into CSR order + permute ea (f16) ----------------
__global__ __launch_bounds__(256) void scatter_kernel(const int* __restrict__ ei,
                                                      u32* __restrict__ cursor,
                                                      int* __restrict__ ssrc,
                                                      const float* __restrict__ ea,
                                                      _Float16* __restrict__ ea_perm) {
    int e = blockIdx.x * 256 + threadIdx.x;
    if (e >= N_EDGES) return;
    int dst = ei[N_EDGES + e];
    u32 pos = atomicAdd(&cursor[dst], 1u);
    ssrc[pos] = ei[e];
    const float4* src = (const float4*)(ea + (size_t)e * EDGE_DIM);
    u32 buf[16];
#pragma unroll
    for (int q = 0; q < 8; q++) {
        float4 v = src[q];
        buf[2 * q + 0] = pack_half2(v.x, v.y);
        buf[2 * q + 1] = pack_half2(v.z, v.w);
    }
    uint4* dp = (uint4*)(ea_perm + (size_t)pos * EDGE_DIM);
#pragma unroll
    for (int q = 0; q < 4; q++)
        dp[q] = make_uint4(buf[4 * q], buf[4 * q + 1], buf[4 * q + 2], buf[4 * q + 3]);
}

// ---------------- weight precompute ----------------
__global__ __launch_bounds__(256) void wconv_kernel(const float* __restrict__ W1,
                                                    const float* __restrict__ W2,
                                                    const float* __restrict__ We,
                                                    _Float16* __restrict__ w1t,
                                                    _Float16* __restrict__ w2t,
                                                    _Float16* __restrict__ weT) {
    int idx = blockIdx.x * 256 + threadIdx.x;
    if (idx < NUM_LAYERS * 128 * 128) {
        int kk = idx & 127, f = (idx >> 7) & 127, l = idx >> 14;
        int w = kk >> 1;
        int k1 = 32 * (w >> 4) + (w & 15) + ((kk & 1) << 4);
        w1t[idx] = (_Float16)W1[l * 16384 + k1 * 128 + f];
        w2t[idx] = (_Float16)W2[l * 16384 + kk * 128 + f];
    }
    if (idx < NUM_LAYERS * 8 * 64) {
        int lane = idx & 63, c = (idx >> 6) & 7, l = idx >> 9;
        int rg = lane >> 4, li = lane & 15;
        _Float16* dst = weT + (size_t)idx * 8;
#pragma unroll
        for (int j = 0; j < 8; j++)
            dst[j] = (_Float16)We[l * (EDGE_DIM * HIDDEN) + (8 * rg + j) * HIDDEN + c * 16 + li];
    }
}

// ---------------- per-node epilogue: reduce acc + self term + store ----------------
__device__ __forceinline__ void agg_epilogue(int node, const f32x4* __restrict__ acc,
                                             const u32* __restrict__ h16p,
                                             u32* __restrict__ z16b,
                                             int li, int rg, int l) {
    float s[8];
#pragma unroll
    for (int c = 0; c < 8; c++) {
        float v = acc[c][0] + acc[c][1] + acc[c][2] + acc[c][3];
        v += __shfl_xor(v, 16);
        v += __shfl_xor(v, 32);
        s[c] = v;
    }
    float x0 = (rg & 1) ? s[2] : s[0];
    float x1 = (rg & 1) ? s[6] : s[4];
    float va = (rg & 2) ? x1 : x0;
    float y0 = (rg & 1) ? s[3] : s[1];
    float y1 = (rg & 1) ? s[7] : s[5];
    float vb = (rg & 2) ? y1 : y0;
    const u32* hp = h16p + (size_t)node * 64 + li * 4 + 2 * (rg & 1);
    u32 ga = hp[0], gb = hp[1];
    float hva = (rg >= 2) ? (float)as_half2(ga).y : (float)as_half2(ga).x;
    float hvb = (rg >= 2) ? (float)as_half2(gb).y : (float)as_half2(gb).x;
    z16b[(size_t)node * 64 + l] = pack_half2(hva + va, hvb + vb);
}

// ---------------- CSR aggregation via MFMA, 3-stage pipelined ----------------
// NPW=4 (12500 waves, max TLP — NPW=16 regressed, m.round10). 2-deep prefetch:
// iteration k issues tile k+2's ssrc+A, tile k+1's gathers (ssrc resolved a
// full iteration ago), computes tile k (gathers in flight a full iteration).
// The ssrc->gather load-to-load chain spans 2 iterations instead of 1.
#define AGG_NPW 4
#define AGG_SLOTS ((N_NODES + AGG_NPW - 1) / AGG_NPW)   // 12500

#define AGG_ADVANCE(ni, eti, e1i, no, eto, e1o, vo) do {                 \
    int _etn = (eti) + 16;                                               \
    if (_etn < (e1i)) { no = (ni); eto = _etn; e1o = (e1i); vo = true; } \
    else {                                                               \
        int _n2 = (ni) + 1; vo = false; no = _n2;                        \
        if (_n2 < nb) {                                                  \
            int _a = (e1i), _b = (int)coff[_n2 + 1];                     \
            while (_a == _b && _n2 + 1 < nb) {                           \
                _n2++; _a = _b; _b = (int)coff[_n2 + 1];                 \
            }                                                            \
            if (_a < _b) { no = _n2; eto = _a; e1o = _b; vo = true; }    \
        }                                                                \
    }                                                                    \
} while (0)

__global__ __launch_bounds__(256) void agg_mfma_kernel(
    const u32* __restrict__ h16p, const _Float16* __restrict__ ea_perm,
    const int* __restrict__ ssrc, const u32* __restrict__ off,
    const _Float16* __restrict__ weT, const float* __restrict__ be,
    u32* __restrict__ z16b) {
    int t = threadIdx.x, l = t & 63, li = l & 15, rg = l >> 4;

    half8 bfrag[8];
    const uint4* wp = (const uint4*)weT;
#pragma unroll
    for (int c = 0; c < 8; c++) {
        union { uint4 u; half8 h; } cv;
        cv.u = wp[c * 64 + l];
        bfrag[c] = cv.h;
    }
    float beC[8];
#pragma unroll
    for (int c = 0; c < 8; c++) beC[c] = be[c * 16 + li];

    const AS4 u32* coff = (const AS4 u32*)(unsigned long long)off;

    int wid = __builtin_amdgcn_readfirstlane(t >> 6);
    int slot = blockIdx.x * 4 + wid;
    if (slot >= AGG_SLOTS) return;
    int na = slot * AGG_NPW;
    int nb = na + AGG_NPW; if (nb > N_NODES) nb = N_NODES;

    f32x4 acc[8];
#pragma unroll
    for (int c = 0; c < 8; c++) acc[c] = (f32x4){0.f, 0.f, 0.f, 0.f};

    // ---- find first tile (t0), emitting leading empty epilogues ----
    int n0 = na;
    int e0 = (int)coff[n0], e1_0 = (int)coff[n0 + 1];
    while (e0 == e1_0) {
        agg_epilogue(n0, acc, h16p, z16b, li, rg, l);
        n0++;
        if (n0 >= nb) return;
        e0 = e1_0; e1_0 = (int)coff[n0 + 1];
    }
    int et0 = e0;

    // ---- prologue: t0 srcs + A + gathers (one-time serial fill) ----
    int eb0 = et0 + 4 * rg;
    int s0 = ssrc[(eb0 + 0 < e1_0) ? eb0 + 0 : et0];
    int s1 = ssrc[(eb0 + 1 < e1_0) ? eb0 + 1 : et0];
    int s2 = ssrc[(eb0 + 2 < e1_0) ? eb0 + 2 : et0];
    int s3 = ssrc[(eb0 + 3 < e1_0) ? eb0 + 3 : et0];
    uint4 A0 = *(const uint4*)(ea_perm + (size_t)(et0 + li) * 32 + rg * 8);
    uint4 gc0 = *(const uint4*)(h16p + (size_t)s0 * 64 + li * 4);
    uint4 gc1 = *(const uint4*)(h16p + (size_t)s1 * 64 + li * 4);
    uint4 gc2 = *(const uint4*)(h16p + (size_t)s2 * 64 + li * 4);
    uint4 gc3 = *(const uint4*)(h16p + (size_t)s3 * 64 + li * 4);

    // ---- t1 = advance(t0); issue t1 srcs + A ----
    int n1 = 0, et1 = 0, e1_1 = 0; bool v1 = false;
    AGG_ADVANCE(n0, et0, e1_0, n1, et1, e1_1, v1);
    int p0 = 0, p1 = 0, p2 = 0, p3 = 0;
    uint4 A1 = A0;
    if (v1) {
        int eb1 = et1 + 4 * rg;
        p0 = ssrc[(eb1 + 0 < e1_1) ? eb1 + 0 : et1];
        p1 = ssrc[(eb1 + 1 < e1_1) ? eb1 + 1 : et1];
        p2 = ssrc[(eb1 + 2 < e1_1) ? eb1 + 2 : et1];
        p3 = ssrc[(eb1 + 3 < e1_1) ? eb1 + 3 : et1];
        A1 = *(const uint4*)(ea_perm + (size_t)(et1 + li) * 32 + rg * 8);
    }

    while (true) {
        // (a) t2 = advance(t1); issue t2 srcs + A
        int n2t = 0, et2 = 0, e1_2 = 0; bool v2 = false;
        int q0 = 0, q1 = 0, q2 = 0, q3 = 0;
        uint4 A2 = A1;
        if (v1) {
            AGG_ADVANCE(n1, et1, e1_1, n2t, et2, e1_2, v2);
            if (v2) {
                int eb2 = et2 + 4 * rg;
                q0 = ssrc[(eb2 + 0 < e1_2) ? eb2 + 0 : et2];
                q1 = ssrc[(eb2 + 1 < e1_2) ? eb2 + 1 : et2];
                q2 = ssrc[(eb2 + 2 < e1_2) ? eb2 + 2 : et2];
                q3 = ssrc[(eb2 + 3 < e1_2) ? eb2 + 3 : et2];
                A2 = *(const uint4*)(ea_perm + (size_t)(et2 + li) * 32 + rg * 8);
            }
        }
        // (b) issue t1's gathers (its ssrc resolved a full iteration ago)
        uint4 gn0 = gc0, gn1 = gc1, gn2 = gc2, gn3 = gc3;
        if (v1) {
            gn0 = *(const uint4*)(h16p + (size_t)p0 * 64 + li * 4);
            gn1 = *(const uint4*)(h16p + (size_t)p1 * 64 + li * 4);
            gn2 = *(const uint4*)(h16p + (size_t)p2 * 64 + li * 4);
            gn3 = *(const uint4*)(h16p + (size_t)p3 * 64 + li * 4);
        }
        // (c) MFMA + masked accumulate for t0 (gathers in flight 1 iteration)
        {
            union { uint4 u; half8 h; } av; av.u = A0;
            int ebase = et0 + 4 * rg;
            bool m0 = (ebase + 0) < e1_0, m1 = (ebase + 1) < e1_0;
            bool m2 = (ebase + 2) < e1_0, m3 = (ebase + 3) < e1_0;
#pragma unroll
            for (int q = 0; q < 4; q++) {
                f32x4 cl = (f32x4){beC[q], beC[q], beC[q], beC[q]};
                f32x4 ch = (f32x4){beC[q + 4], beC[q + 4], beC[q + 4], beC[q + 4]};
                f32x4 dl = __builtin_amdgcn_mfma_f32_16x16x32_f16(av.h, bfrag[q], cl, 0, 0, 0);
                f32x4 dh = __builtin_amdgcn_mfma_f32_16x16x32_f16(av.h, bfrag[q + 4], ch, 0, 0, 0);
                u32 w0 = (&gc0.x)[q], w1 = (&gc1.x)[q], w2 = (&gc2.x)[q], w3 = (&gc3.x)[q];
                float m;
                m = fmaxf(dl[0] + (float)as_half2(w0).x, 0.f); acc[q][0]     += m0 ? m : 0.f;
                m = fmaxf(dh[0] + (float)as_half2(w0).y, 0.f); acc[q + 4][0] += m0 ? m : 0.f;
                m = fmaxf(dl[1] + (float)as_half2(w1).x, 0.f); acc[q][1]     += m1 ? m : 0.f;
                m = fmaxf(dh[1] + (float)as_half2(w1).y, 0.f); acc[q + 4][1] += m1 ? m : 0.f;
                m = fmaxf(dl[2] + (float)as_half2(w2).x, 0.f); acc[q][2]     += m2 ? m : 0.f;
                m = fmaxf(dh[2] + (float)as_half2(w2).y, 0.f); acc[q + 4][2] += m2 ? m : 0.f;
                m = fmaxf(dl[3] + (float)as_half2(w3).x, 0.f); acc[q][3]     += m3 ? m : 0.f;
                m = fmaxf(dh[3] + (float)as_half2(w3).y, 0.f); acc[q + 4][3] += m3 ? m : 0.f;
            }
        }
        // (d) node boundary: emit epilogue(s), reset acc
        if (et0 + 16 >= e1_0) {
            agg_epilogue(n0, acc, h16p, z16b, li, rg, l);
#pragma unroll
            for (int c = 0; c < 8; c++) acc[c] = (f32x4){0.f, 0.f, 0.f, 0.f};
            int mend = v1 ? n1 : nb;
            for (int m = n0 + 1; m < mend; m++)
                agg_epilogue(m, acc, h16p, z16b, li, rg, l);
        }
        if (!v1) break;
        // (e) rotate pipeline
        n0 = n1; et0 = et1; e1_0 = e1_1;
        A0 = A1; gc0 = gn0; gc1 = gn1; gc2 = gn2; gc3 = gn3;
        n1 = n2t; et1 = et2; e1_1 = e1_2; v1 = v2;
        A1 = A2; p0 = q0; p1 = q1; p2 = q2; p3 = q3;
    }
}

// ---------------- fused MLP via MFMA (fp16 in, fp32 accum) ----------------
__global__ __launch_bounds__(256) void mlp_mfma_kernel(
    const u32* __restrict__ z16,
    const _Float16* __restrict__ w1t, const float* __restrict__ b1_,
    const _Float16* __restrict__ w2t, const float* __restrict__ b2_,
    float* __restrict__ z2, float* __restrict__ stats) {
    __shared__ __align__(16) char lds[65536];
    char* zh = lds;            // 32 KB: z tile (k'-order), later h1 tile
    char* wh = lds + 32768;    // 32 KB: W1T, later W2T
    int t = threadIdx.x, l = t & 63, w = t >> 6;
    int li = l & 15, rg = l >> 4;
    int base = blockIdx.x * 128;

    // stage z tile (global uint4 coalesced -> swizzled b128 LDS write)
#pragma unroll
    for (int rep = 0; rep < 8; rep++) {
        int c = t + rep * 256;
        int n = c >> 4, s = c & 15;
        int gn = base + n;
        uint4 v = make_uint4(0u, 0u, 0u, 0u);
        if (gn < N_NODES) v = *(const uint4*)(z16 + (size_t)gn * 64 + s * 4);
        *(uint4*)(zh + n * 256 + ((s ^ (n & 7)) << 4)) = v;
    }
    // stage W1T
#pragma unroll
    for (int rep = 0; rep < 8; rep++) {
        int c = t + rep * 256;
        int f = c >> 4, s = c & 15;
        uint4 v = *(const uint4*)((const char*)w1t + f * 256 + s * 16);
        *(uint4*)(wh + f * 256 + ((s ^ (f & 7)) << 4)) = v;
    }
    __syncthreads();

    int f0 = w * 32 + li;
    int f1 = w * 32 + 16 + li;

    f32x4 acc0[8], acc1[8];
    {
        float bva = b1_[f0], bvb = b1_[f1];
#pragma unroll
        for (int m = 0; m < 8; m++) {
            acc0[m] = (f32x4){bva, bva, bva, bva};
            acc1[m] = (f32x4){bvb, bvb, bvb, bvb};
        }
    }
    // GEMM1: h1 = relu(z @ W1 + b1)
#pragma unroll
    for (int kt = 0; kt < 4; kt++) {
        int s = kt * 4 + rg;
        half8 bf0 = *(const half8*)(wh + f0 * 256 + ((s ^ (f0 & 7)) << 4));
        half8 bf1 = *(const half8*)(wh + f1 * 256 + ((s ^ (f1 & 7)) << 4));
#pragma unroll
        for (int m = 0; m < 8; m++) {
            int n = m * 16 + li;
            half8 af = *(const half8*)(zh + n * 256 + ((s ^ (n & 7)) << 4));
            acc0[m] = __builtin_amdgcn_mfma_f32_16x16x32_f16(af, bf0, acc0[m], 0, 0, 0);
            acc1[m] = __builtin_amdgcn_mfma_f32_16x16x32_f16(af, bf1, acc1[m], 0, 0, 0);
        }
    }
    __syncthreads();   // all GEMM1 reads of zh/wh complete

    // write h1 (relu, fp16) into zh at [node][feat] (identity k for GEMM2)
#pragma unroll
    for (int m = 0; m < 8; m++) {
#pragma unroll
        for (int r = 0; r < 4; r++) {
            int n = m * 16 + rg * 4 + r;
            int s0 = f0 >> 3;
            *(_Float16*)(zh + n * 256 + ((s0 ^ (n & 7)) << 4) + (f0 & 7) * 2) =
                (_Float16)fmaxf(acc0[m][r], 0.f);
            int s1 = f1 >> 3;
            *(_Float16*)(zh + n * 256 + ((s1 ^ (n & 7)) << 4) + (f1 & 7) * 2) =
                (_Float16)fmaxf(acc1[m][r], 0.f);
        }
    }
    // stage W2T into wh
#pragma unroll
    for (int rep = 0; rep < 8; rep++) {
        int c = t + rep * 256;
        int f = c >> 4, s = c & 15;
        uint4 v = *(const uint4*)((const char*)w2t + f * 256 + s * 16);
        *(uint4*)(wh + f * 256 + ((s ^ (f & 7)) << 4)) = v;
    }
    __syncthreads();

    // GEMM2: z2 = h1 @ W2 + b2
    {
        float cva = b2_[f0], cvb = b2_[f1];
#pragma unroll
        for (int m = 0; m < 8; m++) {
            acc0[m] = (f32x4){cva, cva, cva, cva};
            acc1[m] = (f32x4){cvb, cvb, cvb, cvb};
        }
    }
#pragma unroll
    for (int kt = 0; kt < 4; kt++) {
        int s = kt * 4 + rg;
        half8 bf0 = *(const half8*)(wh + f0 * 256 + ((s ^ (f0 & 7)) << 4));
        half8 bf1 = *(const half8*)(wh + f1 * 256 + ((s ^ (f1 & 7)) << 4));
#pragma unroll
        for (int m = 0; m < 8; m++) {
            int n = m * 16 + li;
            half8 af = *(const half8*)(zh + n * 256 + ((s ^ (n & 7)) << 4));
            acc0[m] = __builtin_amdgcn_mfma_f32_16x16x32_f16(af, bf0, acc0[m], 0, 0, 0);
            acc1[m] = __builtin_amdgcn_mfma_f32_16x16x32_f16(af, bf1, acc1[m], 0, 0, 0);
        }
    }

    // epilogue: store z2 (fp32) + fused BN stats
    float s0 = 0.f, q0 = 0.f, s1 = 0.f, q1 = 0.f;
#pragma unroll
    for (int m = 0; m < 8; m++) {
#pragma unroll
        for (int r = 0; r < 4; r++) {
            int gn = base + m * 16 + rg * 4 + r;
            if (gn < N_NODES) {
                float v0 = acc0[m][r], v1 = acc1[m][r];
                z2[(size_t)gn * 128 + f0] = v0;
                z2[(size_t)gn * 128 + f1] = v1;
                s0 += v0; q0 = fmaf(v0, v0, q0);
                s1 += v1; q1 = fmaf(v1, v1, q1);
            }
        }
    }
    s0 += __shfl_xor(s0, 16); s0 += __shfl_xor(s0, 32);
    q0 += __shfl_xor(q0, 16); q0 += __shfl_xor(q0, 32);
    s1 += __shfl_xor(s1, 16); s1 += __shfl_xor(s1, 32);
    q1 += __shfl_xor(q1, 16); q1 += __shfl_xor(q1, 32);
    if (rg == 0) {
        unsafeAtomicAdd(&stats[f0], s0);
        unsafeAtomicAdd(&stats[128 + f0], q0);
        unsafeAtomicAdd(&stats[f1], s1);
        unsafeAtomicAdd(&stats[128 + f1], q1);
    }
}

// ---------------- batchnorm + relu + residual (h16p layout) ----------------
__global__ __launch_bounds__(256) void bn_kernel(
    const float* __restrict__ z2, const float* __restrict__ stats,
    const float* __restrict__ gamma, const float* __restrict__ beta,
    u32* __restrict__ h16, float* __restrict__ out, int write_out) {
    int idx = blockIdx.x * 256 + threadIdx.x;
    if (idx >= N_NODES * 64) return;
    int n = idx >> 6, w = idx & 63;
    int li = w >> 2, q = w & 3;
    int f = q * 16 + li, fh = f + 64;
    const float inv_n = 1.0f / (float)N_NODES;
    float mu_l = stats[f] * inv_n;
    float mu_h = stats[fh] * inv_n;
    float var_l = stats[HIDDEN + f] * inv_n - mu_l * mu_l;
    float var_h = stats[HIDDEN + fh] * inv_n - mu_h * mu_h;
    float inv_l = rsqrtf(var_l + BN_EPS);
    float inv_h = rsqrtf(var_h + BN_EPS);
    float zl = (z2[n * HIDDEN + f]  - mu_l) * inv_l * gamma[f]  + beta[f];
    float zh = (z2[n * HIDDEN + fh] - mu_h) * inv_h * gamma[fh] + beta[fh];
    zl = fmaxf(zl, 0.f);
    zh = fmaxf(zh, 0.f);
    half2_t hh = as_half2(h16[idx]);
    float hn_l = fmaf(RES_SCALE, (float)hh.x, zl);
    float hn_h = fmaf(RES_SCALE, (float)hh.y, zh);
    h16[idx] = pack_half2(hn_l, hn_h);
    if (write_out) {
        out[n * HIDDEN + f]  = hn_l;
        out[n * HIDDEN + fh] = hn_h;
    }
}

extern "C" void kernel_launch(void* const* d_in, const int* in_sizes, int n_in,
                              void* d_out, int out_size, void* d_ws, size_t ws_size,
                              hipStream_t stream) {
    const float* x     = (const float*)d_in[0];
    const int*   ei    = (const int*)d_in[1];
    const float* ea    = (const float*)d_in[2];
    const float* We    = (const float*)d_in[3];
    const float* be    = (const float*)d_in[4];
    const float* W1    = (const float*)d_in[5];
    const float* b1    = (const float*)d_in[6];
    const float* W2    = (const float*)d_in[7];
    const float* b2    = (const float*)d_in[8];
    const float* gamma = (const float*)d_in[9];
    const float* beta  = (const float*)d_in[10];
    float* out = (float*)d_out;

    char* wsp = (char*)d_ws;
    const size_t NH = (size_t)N_NODES * HIDDEN;
    u32*      h16    = (u32*)wsp;      wsp += (size_t)N_NODES * 64 * 4;        // 12.8 MB
    u32*      z16    = (u32*)wsp;      wsp += (size_t)N_NODES * 64 * 4;        // 12.8 MB
    float*    z2     = (float*)wsp;    wsp += NH * 4;                          // 25.6 MB
    _Float16* ea_perm= (_Float16*)wsp; wsp += (size_t)N_EDGES * EDGE_DIM * 2;  // 51.2 MB
    _Float16* w1t    = (_Float16*)wsp; wsp += (size_t)NUM_LAYERS * 128 * 128 * 2;
    _Float16* w2t    = (_Float16*)wsp; wsp += (size_t)NUM_LAYERS * 128 * 128 * 2;
    _Float16* weT    = (_Float16*)wsp; wsp += (size_t)NUM_LAYERS * 4096 * 2;
    float*    statsA = (float*)wsp;    wsp += (size_t)NUM_LAYERS * 256 * 4;
    u32*      deg    = (u32*)wsp;      wsp += (size_t)N_NODES * 4;
    u32*      cursor = (u32*)wsp;      wsp += (size_t)N_NODES * 4;
    int*      ssrc   = (int*)wsp;      wsp += (size_t)N_EDGES * 4;
    u32*      off    = (u32*)wsp;      wsp += (size_t)(N_NODES + 1) * 4;
    u32*      bsum   = (u32*)wsp;      wsp += (size_t)SCAN_NB * 4;
    u32*      bbase  = (u32*)wsp;      wsp += (size_t)SCAN_NB * 4;

    const int p_blocks  = (N_NODES * 64 + 255) / 256;       // 12500
    const int e_blocks  = (N_EDGES + 255) / 256;            // 3125
    const int m_blocks  = (N_NODES + 127) / 128;            // 391
    const int a_blocks  = (AGG_SLOTS + 3) / 4;              // 3125
    const int w_blocks  = (NUM_LAYERS * 128 * 128 + 255) / 256; // 192

    // CSR build + weight precompute (once per call)
    init_kernel<<<p_blocks, 256, 0, stream>>>(x, h16, deg, statsA);
    hist_kernel<<<e_blocks, 256, 0, stream>>>(ei, deg);
    scan1_kernel<<<SCAN_NB, 256, 0, stream>>>(deg, bsum);
    scan2_kernel<<<1, 256, 0, stream>>>(bsum, bbase, off);
    scan3_kernel<<<SCAN_NB, 256, 0, stream>>>(deg, bbase, off, cursor);
    scatter_kernel<<<e_blocks, 256, 0, stream>>>(ei, cursor, ssrc, ea, ea_perm);
    wconv_kernel<<<w_blocks, 256, 0, stream>>>(W1, W2, We, w1t, w2t, weT);

    for (int l = 0; l < NUM_LAYERS; l++) {
        agg_mfma_kernel<<<a_blocks, 256, 0, stream>>>(
            h16, ea_perm, ssrc, off,
            weT + (size_t)l * 4096, be + (size_t)l * HIDDEN, z16);
        mlp_mfma_kernel<<<m_blocks, 256, 0, stream>>>(
            z16, w1t + (size_t)l * 16384, b1 + (size_t)l * HIDDEN,
            w2t + (size_t)l * 16384, b2 + (size_t)l * HIDDEN,
            z2, statsA + (size_t)l * 256);
        bn_kernel<<<p_blocks, 256, 0, stream>>>(
            z2, statsA + (size_t)l * 256, gamma + (size_t)l * HIDDEN, beta + (size_t)l * HIDDEN,
            h16, out, (l == NUM_LAYERS - 1) ? 1 : 0);
    }
}